// Round 23
// baseline (30.866 us; speedup 1.0000x reference)
//
#include <hip/hip_runtime.h>

// Denoiser MLP (2->16, 5x 16->16, 16->2), fp32 in/out, via v_mfma_f32_16x16x16_f16.
// R23 = R22/R17 base with the input layer moved OFF the matrix pipe.
// Rationale: CDNA4 MFMA executes on the SIMD units -> matrix+VALU cycles are
// additive (fits R17-R22: 10us matrix + 7us VALU + exposure = 27.9). The 4
// input-layer MFMAs are 7/8 empty (2 of 16 k-cols nonzero): 54 matrix
// cyc/body for 2 FMA/point. Replaced with packed-f32 VALU (R4-proven,
// ~16 instr/body) + per-tile loads (same 16 points re-read by all 4 lane
// groups -> L1 broadcast, zero extra HBM). Matrix term 28->24 MFMA/body.
//
// Mapping (verified R3/R17/R22, absmax 7.8e-3):
//   per layer D = A*B, A = weights (16x16), B = activations^T
//   A frag: lane l holds A[i=l&15][k=4*(l>>4)+j], j=0..3
//   B frag: lane l holds B[k=4*(l>>4)+j][n=l&15]
//   D frag: lane l holds D[i=4*(l>>4)+r][n=l&15], r=0..3
//   D layout == B layout -> layers chain in-register, zero cross-lane.
// Input layer (VALU): lane (g,nn) computes features 4g..4g+3 of point
// base+16t+nn for tile t: a = wic0*x + wic1*y (f32), then cvt_relu4 ->
// exactly the B-frag layout. wic0/wic1 = w_in columns for rows 4g..4g+3.
// Output: wo rows 0,1 -> D regs 0,1 @ group 0 (lanes 0-15), masked store.

typedef _Float16 h4v __attribute__((ext_vector_type(4)));
typedef float f4 __attribute__((ext_vector_type(4)));
typedef float f2 __attribute__((ext_vector_type(2)));
typedef unsigned int u32;
typedef u32 u2v __attribute__((ext_vector_type(2)));

static __device__ __forceinline__ f4 mfma16(h4v a, h4v b, f4 c) {
    return __builtin_amdgcn_mfma_f32_16x16x16f16(a, b, c, 0, 0, 0);
}

static __device__ __forceinline__ u32 cvtpk(float a, float b) {
    return __builtin_bit_cast(u32, __builtin_amdgcn_cvt_pkrtz(a, b));
}

static __device__ __forceinline__ h4v pack2(u32 lo, u32 hi) {
    u2v p = {lo, hi};
    return __builtin_bit_cast(h4v, p);
}

// weight A-fragment: row = given, cols 4g..4g+3
static __device__ __forceinline__ h4v wfrag(const float* row, int g) {
    const f4* r4 = (const f4*)row;
    f4 q = r4[g];
    return pack2(cvtpk(q.x, q.y), cvtpk(q.z, q.w));
}

// relu + cvt of 4 f32 -> B fragment (order-preserving)
static __device__ __forceinline__ h4v cvt_relu4(f4 a) {
    h4v hb = pack2(cvtpk(a[0], a[1]), cvtpk(a[2], a[3]));
    const h4v z = {};
    return __builtin_elementwise_max(hb, z);   // 2x v_pk_max_f16
}

__global__ __launch_bounds__(256, 5) void denoiser_mfma16(
    const f2* __restrict__ x,        // [N] points (x0,x1)
    const float* __restrict__ w_in,  // [16][2]
    const float* __restrict__ w_mid, // [5][16][16]
    const float* __restrict__ w_out, // [2][16]
    f2* __restrict__ out,            // [N] (o0,o1)
    int n)
{
    const int lane = threadIdx.x & 63;
    const int nn   = lane & 15;   // point-in-tile / A-row
    const int g    = lane >> 4;   // k-group (4 features per group)
    const int wave = threadIdx.x >> 6;

    const h4v hz = {};

    // ---- one-time weight fragments ----
    // input layer (VALU): wic0/wic1 = w_in[4g+j][0], w_in[4g+j][1], j=0..3
    f4 wic0, wic1;
    {
        const f4* w4 = (const f4*)w_in;   // 8x float4 over [16][2]
        f4 a = w4[2 * g], b = w4[2 * g + 1];
        wic0 = (f4){a.x, a.z, b.x, b.z};
        wic1 = (f4){a.y, a.w, b.y, b.w};
    }

    h4v wm0 = wfrag(w_mid + 0 * 256 + nn * 16, g);
    h4v wm1 = wfrag(w_mid + 1 * 256 + nn * 16, g);
    h4v wm2 = wfrag(w_mid + 2 * 256 + nn * 16, g);
    h4v wm3 = wfrag(w_mid + 3 * 256 + nn * 16, g);
    h4v wm4 = wfrag(w_mid + 4 * 256 + nn * 16, g);

    h4v wo = nn < 2 ? wfrag(w_out + nn * 16, g) : hz;

    // one-time pin: zero C-operand (4 regs) resident, un-rematerializable
    f4 z4 = {};
    asm("" : "+v"(z4));

    const int nchunks = (n + 255) >> 8;     // 256-pt block chunks
    const int stride  = gridDim.x;
    const int nm1     = n - 1;

    // tile-t load: lane (g,nn) reads point c*256 + wave*64 + 16t + nn
    // (same 16 points for all 4 groups -> L1 broadcast; no extra HBM)
    auto loadxt = [&](int c, int t) -> f2 {
        int pi = c * 256 + wave * 64 + t * 16 + nn;
        return x[pi < n ? pi : nm1];
    };

    int c = blockIdx.x;
    f2 xy0 = loadxt(c, 0), xy1 = loadxt(c, 1);
    f2 xy2 = loadxt(c, 2), xy3 = loadxt(c, 3);

    for (; c < nchunks; c += stride) {
        // depth-1 prefetch of next chunk (issued before the compute chain)
        const int cn = c + stride;
        const int cp = cn < nchunks ? cn : c;
        f2 xn0 = loadxt(cp, 0), xn1 = loadxt(cp, 1);
        f2 xn2 = loadxt(cp, 2), xn3 = loadxt(cp, 3);

        const int base = c * 256 + wave * 64;

        // ---- input layer on VALU (packed f32): B-frag direct ----
        h4v b0 = cvt_relu4(wic0 * xy0.x + wic1 * xy0.y);
        h4v b1 = cvt_relu4(wic0 * xy1.x + wic1 * xy1.y);
        h4v b2 = cvt_relu4(wic0 * xy2.x + wic1 * xy2.y);
        h4v b3 = cvt_relu4(wic0 * xy3.x + wic1 * xy3.y);

        f4 a0, a1, a2, a3;

        // ---- 5 mid layers: 4 independent tiles (ILP) ----
        #define MIDLAYER(W)                                    \
            a0 = mfma16(W, b0, z4);  a1 = mfma16(W, b1, z4);   \
            a2 = mfma16(W, b2, z4);  a3 = mfma16(W, b3, z4);   \
            b0 = cvt_relu4(a0);  b1 = cvt_relu4(a1);           \
            b2 = cvt_relu4(a2);  b3 = cvt_relu4(a3);
        MIDLAYER(wm0)
        MIDLAYER(wm1)
        MIDLAYER(wm2)
        MIDLAYER(wm3)
        MIDLAYER(wm4)
        #undef MIDLAYER

        // ---- output layer: rows 0,1 -> regs 0,1 @ group 0 ----
        a0 = mfma16(wo, b0, z4);
        a1 = mfma16(wo, b1, z4);
        a2 = mfma16(wo, b2, z4);
        a3 = mfma16(wo, b3, z4);

        if (lane < 16) {
            int p0 = base + nn;
            if (base + 64 <= n) {
                out[p0]      = (f2){a0[0], a0[1]};
                out[p0 + 16] = (f2){a1[0], a1[1]};
                out[p0 + 32] = (f2){a2[0], a2[1]};
                out[p0 + 48] = (f2){a3[0], a3[1]};
            } else {
                if (p0 < n)      out[p0]      = (f2){a0[0], a0[1]};
                if (p0 + 16 < n) out[p0 + 16] = (f2){a1[0], a1[1]};
                if (p0 + 32 < n) out[p0 + 32] = (f2){a2[0], a2[1]};
                if (p0 + 48 < n) out[p0 + 48] = (f2){a3[0], a3[1]};
            }
        }

        xy0 = xn0; xy1 = xn1; xy2 = xn2; xy3 = xn3;
    }
}

extern "C" void kernel_launch(void* const* d_in, const int* in_sizes, int n_in,
                              void* d_out, int out_size, void* d_ws, size_t ws_size,
                              hipStream_t stream) {
    const float* x     = (const float*)d_in[0];
    const float* w_in  = (const float*)d_in[1];
    const float* w_mid = (const float*)d_in[2];
    const float* w_out = (const float*)d_in[3];

    int n = in_sizes[0] / 2;          // number of points
    int nchunks = (n + 255) / 256;
    int blocks = nchunks < 2048 ? nchunks : 2048;  // persistent

    denoiser_mfma16<<<blocks, 256, 0, stream>>>(
        (const f2*)x, w_in, w_mid, w_out, (f2*)d_out, n);
}

// Round 24
// 27.599 us; speedup vs baseline: 1.1184x; 1.1184x over previous
//
#include <hip/hip_runtime.h>

// Denoiser MLP (2->16, 5x 16->16, 16->2), fp32 in/out, via v_mfma_f32_16x16x16_f16.
// R24 = final restore of the session optimum (R17, confirmed twice:
// 27.66 / 27.97 us). R23's VALU-input-layer variant regressed (+2.9us:
// 4x VMEM issue duplication > 54 matrix-cyc saved) -- the MFMA input layer
// (1 load + 1 cvtpk + 4 group-select MFMAs per 64 pts) is optimal.
//
// Final model (fits R3-R23): dur ~= matrix(~10us: 28 MFMA/body x 13.45
// cyc/SIMD) + VALU(~7us) + memory/latency exposure(~10us). Tested & priced:
// shapes (16x16x16 best/useful-FLOP; K32-pad +30%, 32x32-dup worse),
// accumulator footprint (R17's 4-reg tuples: the -16% win), ILP 1-8 chains
// (null), waves 2.6-5/SIMD (null), non-persistent launch (+55%), prefetch
// d1/d2 (null), setprio (null), s_sleep stagger (null), coalesced stores
// (null), pipe migration (regression). Practical plateau ~27.7us.
//
// Mapping (verified R3/R17/R22, absmax 7.8e-3):
//   per layer D = A*B, A = weights (16x16), B = activations^T
//   A frag: lane l holds A[i=l&15][k=4*(l>>4)+j], j=0..3
//   B frag: lane l holds B[k=4*(l>>4)+j][n=l&15]
//   D frag: lane l holds D[i=4*(l>>4)+r][n=l&15], r=0..3
//   D layout == B layout -> layers chain in-register, zero cross-lane.
// Input trick: bin = pack2(cvtpk(x,y),0) puts lane l's point at k=4g+{0,1},
// col l&15; wi_t (W_in at k-slots {4t,4t+1}, held by g==t lanes) selects
// group-t lanes' points -> tile t = pts base+16t..16t+15; one cvtpk feeds
// all 4 input MFMAs. Output: wo rows 0,1 -> D regs 0,1 @ group 0.

typedef _Float16 h4v __attribute__((ext_vector_type(4)));
typedef float f4 __attribute__((ext_vector_type(4)));
typedef float f2 __attribute__((ext_vector_type(2)));
typedef unsigned int u32;
typedef u32 u2v __attribute__((ext_vector_type(2)));

static __device__ __forceinline__ f4 mfma16(h4v a, h4v b, f4 c) {
    return __builtin_amdgcn_mfma_f32_16x16x16f16(a, b, c, 0, 0, 0);
}

static __device__ __forceinline__ u32 cvtpk(float a, float b) {
    return __builtin_bit_cast(u32, __builtin_amdgcn_cvt_pkrtz(a, b));
}

static __device__ __forceinline__ h4v pack2(u32 lo, u32 hi) {
    u2v p = {lo, hi};
    return __builtin_bit_cast(h4v, p);
}

// weight A-fragment: rows = lane&15, cols 4g..4g+3
static __device__ __forceinline__ h4v wfrag(const float* row, int g) {
    const f4* r4 = (const f4*)row;
    f4 q = r4[g];
    return pack2(cvtpk(q.x, q.y), cvtpk(q.z, q.w));
}

// relu + cvt of D regs 0-3 -> next layer's B fragment (order-preserving)
static __device__ __forceinline__ h4v cvt_relu4(f4 a) {
    h4v hb = pack2(cvtpk(a[0], a[1]), cvtpk(a[2], a[3]));
    const h4v z = {};
    return __builtin_elementwise_max(hb, z);   // 2x v_pk_max_f16
}

__global__ __launch_bounds__(256, 5) void denoiser_mfma16(
    const f2* __restrict__ x,        // [N] points (x0,x1)
    const float* __restrict__ w_in,  // [16][2]
    const float* __restrict__ w_mid, // [5][16][16]
    const float* __restrict__ w_out, // [2][16]
    f2* __restrict__ out,            // [N] (o0,o1)
    int n)
{
    const int lane = threadIdx.x & 63;
    const int nn   = lane & 15;   // A-row / point-in-tile
    const int g    = lane >> 4;   // k-group (4 k per group)
    const int wave = threadIdx.x >> 6;

    const h4v hz = {};

    // ---- one-time weight fragments ----
    // input variants: wi_t nonzero only for g==t lanes, k-slots j0,j1 = W_in row
    u32 wxy = cvtpk(w_in[2 * nn], w_in[2 * nn + 1]);
    h4v wi0 = g == 0 ? pack2(wxy, 0u) : hz;
    h4v wi1 = g == 1 ? pack2(wxy, 0u) : hz;
    h4v wi2 = g == 2 ? pack2(wxy, 0u) : hz;
    h4v wi3 = g == 3 ? pack2(wxy, 0u) : hz;

    h4v wm0 = wfrag(w_mid + 0 * 256 + nn * 16, g);
    h4v wm1 = wfrag(w_mid + 1 * 256 + nn * 16, g);
    h4v wm2 = wfrag(w_mid + 2 * 256 + nn * 16, g);
    h4v wm3 = wfrag(w_mid + 3 * 256 + nn * 16, g);
    h4v wm4 = wfrag(w_mid + 4 * 256 + nn * 16, g);

    h4v wo = nn < 2 ? wfrag(w_out + nn * 16, g) : hz;

    // one-time pin: zero C-operand (4 regs) resident, un-rematerializable
    f4 z4 = {};
    asm("" : "+v"(z4));

    const int nchunks = (n + 255) >> 8;     // 256-pt block chunks
    const int stride  = gridDim.x;
    const int nm1     = n - 1;

    auto loadx = [&](int c) -> f2 {
        int pi = c * 256 + wave * 64 + lane;
        return x[pi < n ? pi : nm1];
    };

    int c = blockIdx.x;
    f2 xy = loadx(c);

    for (; c < nchunks; c += stride) {
        // depth-1 prefetch of next chunk (issued before the compute chain)
        const int cn = c + stride;
        f2 xyn = loadx(cn < nchunks ? cn : c);

        const int base = c * 256 + wave * 64;

        // ---- input layer: ONE packed bin, 4 group-selecting A variants ----
        h4v bin = pack2(cvtpk(xy.x, xy.y), 0u);
        f4 a0 = mfma16(wi0, bin, z4);   // pts base+ 0..15
        f4 a1 = mfma16(wi1, bin, z4);   // pts base+16..31
        f4 a2 = mfma16(wi2, bin, z4);   // pts base+32..47
        f4 a3 = mfma16(wi3, bin, z4);   // pts base+48..63
        h4v b0 = cvt_relu4(a0);
        h4v b1 = cvt_relu4(a1);
        h4v b2 = cvt_relu4(a2);
        h4v b3 = cvt_relu4(a3);

        // ---- 5 mid layers: 4 independent tiles (ILP) ----
        a0 = mfma16(wm0, b0, z4);  a1 = mfma16(wm0, b1, z4);
        a2 = mfma16(wm0, b2, z4);  a3 = mfma16(wm0, b3, z4);
        b0 = cvt_relu4(a0);  b1 = cvt_relu4(a1);
        b2 = cvt_relu4(a2);  b3 = cvt_relu4(a3);

        a0 = mfma16(wm1, b0, z4);  a1 = mfma16(wm1, b1, z4);
        a2 = mfma16(wm1, b2, z4);  a3 = mfma16(wm1, b3, z4);
        b0 = cvt_relu4(a0);  b1 = cvt_relu4(a1);
        b2 = cvt_relu4(a2);  b3 = cvt_relu4(a3);

        a0 = mfma16(wm2, b0, z4);  a1 = mfma16(wm2, b1, z4);
        a2 = mfma16(wm2, b2, z4);  a3 = mfma16(wm2, b3, z4);
        b0 = cvt_relu4(a0);  b1 = cvt_relu4(a1);
        b2 = cvt_relu4(a2);  b3 = cvt_relu4(a3);

        a0 = mfma16(wm3, b0, z4);  a1 = mfma16(wm3, b1, z4);
        a2 = mfma16(wm3, b2, z4);  a3 = mfma16(wm3, b3, z4);
        b0 = cvt_relu4(a0);  b1 = cvt_relu4(a1);
        b2 = cvt_relu4(a2);  b3 = cvt_relu4(a3);

        a0 = mfma16(wm4, b0, z4);  a1 = mfma16(wm4, b1, z4);
        a2 = mfma16(wm4, b2, z4);  a3 = mfma16(wm4, b3, z4);
        b0 = cvt_relu4(a0);  b1 = cvt_relu4(a1);
        b2 = cvt_relu4(a2);  b3 = cvt_relu4(a3);

        // ---- output layer: rows 0,1 -> regs 0,1 @ group 0 ----
        a0 = mfma16(wo, b0, z4);
        a1 = mfma16(wo, b1, z4);
        a2 = mfma16(wo, b2, z4);
        a3 = mfma16(wo, b3, z4);

        if (lane < 16) {
            int p0 = base + nn;
            if (base + 64 <= n) {
                out[p0]      = (f2){a0[0], a0[1]};
                out[p0 + 16] = (f2){a1[0], a1[1]};
                out[p0 + 32] = (f2){a2[0], a2[1]};
                out[p0 + 48] = (f2){a3[0], a3[1]};
            } else {
                if (p0 < n)      out[p0]      = (f2){a0[0], a0[1]};
                if (p0 + 16 < n) out[p0 + 16] = (f2){a1[0], a1[1]};
                if (p0 + 32 < n) out[p0 + 32] = (f2){a2[0], a2[1]};
                if (p0 + 48 < n) out[p0 + 48] = (f2){a3[0], a3[1]};
            }
        }

        xy = xyn;
    }
}

extern "C" void kernel_launch(void* const* d_in, const int* in_sizes, int n_in,
                              void* d_out, int out_size, void* d_ws, size_t ws_size,
                              hipStream_t stream) {
    const float* x     = (const float*)d_in[0];
    const float* w_in  = (const float*)d_in[1];
    const float* w_mid = (const float*)d_in[2];
    const float* w_out = (const float*)d_in[3];

    int n = in_sizes[0] / 2;          // number of points
    int nchunks = (n + 255) / 256;
    int blocks = nchunks < 2048 ? nchunks : 2048;  // persistent

    denoiser_mfma16<<<blocks, 256, 0, stream>>>(
        (const f2*)x, w_in, w_mid, w_out, (f2*)d_out, n);
}